// Round 3
// baseline (1507.176 us; speedup 1.0000x reference)
//
#include <hip/hip_runtime.h>
#include <stdint.h>

#define KVOL 27
#define CIN  32
#define COUT 64
#define KPG  3           // kernel offsets per wave
#define NGRP 9           // waves per block (KVOL / KPG)
#define RB   64          // output rows per block
#define SCAN_CHUNK 4096  // 256 threads * 16

typedef __attribute__((ext_vector_type(8))) short bf16x8;
typedef __attribute__((ext_vector_type(4))) float f32x4;

__device__ __forceinline__ ushort f2bf(float f) {
  uint32_t u = __float_as_uint(f);
  u += 0x7FFFu + ((u >> 16) & 1u);   // round-to-nearest-even
  return (ushort)(u >> 16);
}

// ---------------------------------------------------------------------------
// feat fp32 -> bf16 (row-major [N][CIN], 64B rows)
// ---------------------------------------------------------------------------
__global__ __launch_bounds__(256) void feat_cvt_kernel(const float* __restrict__ feat,
                                                       ushort* __restrict__ feat16,
                                                       int total4) {
  int i = blockIdx.x * 256 + threadIdx.x;
  if (i < total4) {
    float4 v = ((const float4*)feat)[i];
    ushort4 o;
    o.x = f2bf(v.x); o.y = f2bf(v.y); o.z = f2bf(v.z); o.w = f2bf(v.w);
    ((ushort4*)feat16)[i] = o;
  }
}

// ---------------------------------------------------------------------------
// weights fp32 [KVOL][CIN][COUT] -> bf16 B-fragment layout kernT[ko][ct][col][32k]
// so a lane's 8 contiguous k-elements are one 16B load.
// ---------------------------------------------------------------------------
__global__ __launch_bounds__(256) void kern_cvt_kernel(const float* __restrict__ kern,
                                                       ushort* __restrict__ kernT) {
  int tid = blockIdx.x * 256 + threadIdx.x;       // KVOL*256 threads
  int kc   = tid & 3;          // k-chunk of 8
  int colq = (tid >> 2) & 15;  // cout within tile
  int ct   = (tid >> 6) & 3;   // cout tile
  int ko   = tid >> 8;         // kernel offset
  if (ko >= KVOL) return;
  const float* src = kern + (size_t)ko * CIN * COUT + ct * 16 + colq;
  ushort tmp[8];
#pragma unroll
  for (int j = 0; j < 8; ++j) tmp[j] = f2bf(src[(size_t)(kc * 8 + j) * COUT]);
  ushort* dst = kernT + (((size_t)(ko * 4 + ct) * 16 + colq) * 32 + kc * 8);
#pragma unroll
  for (int j = 0; j < 8; ++j) dst[j] = tmp[j];
}

// ---------------------------------------------------------------------------
// histogram over (out_block, k) bins
// ---------------------------------------------------------------------------
__global__ __launch_bounds__(256) void hist_kernel(const int2* __restrict__ kmap,
                                                   int* __restrict__ count, int M) {
  int m = blockIdx.x * 256 + threadIdx.x;
  int k = blockIdx.y;
  if (m < M) {
    int2 p = kmap[(size_t)k * M + m];
    atomicAdd(&count[(p.y >> 6) * KVOL + k], 1);
  }
}

// ---------------------------------------------------------------------------
// scan (3 kernels, generic over nb)
// ---------------------------------------------------------------------------
__global__ __launch_bounds__(256) void scan_reduce(const int* __restrict__ count,
                                                   int* __restrict__ partial, int nb) {
  __shared__ int ws[4];
  int t = threadIdx.x;
  int base = blockIdx.x * SCAN_CHUNK + t * 16;
  int s = 0;
#pragma unroll
  for (int i = 0; i < 16; ++i) { int idx = base + i; if (idx < nb) s += count[idx]; }
  for (int d = 32; d; d >>= 1) s += __shfl_down(s, d);
  if ((t & 63) == 0) ws[t >> 6] = s;
  __syncthreads();
  if (t == 0) partial[blockIdx.x] = ws[0] + ws[1] + ws[2] + ws[3];
}

__global__ __launch_bounds__(64) void scan_partials(int* __restrict__ partial,
                                                    int nchunks, int* __restrict__ total_out) {
  int lane = threadIdx.x;
  int run = 0;
  for (int base = 0; base < nchunks; base += 64) {
    int i = base + lane;
    int orig = (i < nchunks) ? partial[i] : 0;
    int v = orig;
    for (int d = 1; d < 64; d <<= 1) { int u = __shfl_up(v, d); if (lane >= d) v += u; }
    if (i < nchunks) partial[i] = run + v - orig;   // exclusive
    run += __shfl(v, 63);
  }
  if (lane == 0) *total_out = run;
}

__global__ __launch_bounds__(256) void scan_down(const int* __restrict__ count,
                                                 const int* __restrict__ partial,
                                                 int* __restrict__ start,
                                                 int* __restrict__ cursor, int nb) {
  __shared__ int wsum[4];
  int t = threadIdx.x, blk = blockIdx.x;
  int base = blk * SCAN_CHUNK + t * 16;
  int v[16]; int s = 0;
#pragma unroll
  for (int i = 0; i < 16; ++i) { int idx = base + i; v[i] = (idx < nb) ? count[idx] : 0; s += v[i]; }
  int lane = t & 63, wv = t >> 6;
  int sv = s;
  for (int d = 1; d < 64; d <<= 1) { int u = __shfl_up(sv, d); if (lane >= d) sv += u; }
  if (lane == 63) wsum[wv] = sv;
  __syncthreads();
  int wbase = 0;
  for (int i = 0; i < wv; ++i) wbase += wsum[i];
  int prefix = partial[blk] + wbase + (sv - s);
#pragma unroll
  for (int i = 0; i < 16; ++i) {
    int idx = base + i;
    if (idx < nb) { start[idx] = prefix; cursor[idx] = prefix; }
    prefix += v[i];
  }
}

// ---------------------------------------------------------------------------
// scatter pairs into bins: entry = in | k<<18 | (out&63)<<23
// ---------------------------------------------------------------------------
__global__ __launch_bounds__(256) void scatter_kernel(const int2* __restrict__ kmap,
                                                      int* __restrict__ cursor,
                                                      uint32_t* __restrict__ binned, int M) {
  int m = blockIdx.x * 256 + threadIdx.x;
  int k = blockIdx.y;
  if (m < M) {
    int2 p = kmap[(size_t)k * M + m];
    int bin = (p.y >> 6) * KVOL + k;
    int pos = atomicAdd(&cursor[bin], 1);
    binned[pos] = (uint32_t)p.x | ((uint32_t)k << 18) | ((uint32_t)(p.y & 63) << 23);
  }
}

// ---------------------------------------------------------------------------
// main: block = 9 waves x 64 rows. Wave w owns offsets 3w..3w+2 (weights in
// VGPR B-frags). Per 16 entries: gather A-frags (one 16B load/lane),
// 4x mfma_f32_16x16x32_bf16, scatter D into LDS tile via ds_add_f32.
// Block writes tile + bias once, non-atomically.
// ---------------------------------------------------------------------------
__global__ __launch_bounds__(NGRP * 64) void conv_mfma_kernel(
    const ushort* __restrict__ feat16,    // [N][CIN] bf16
    const uint32_t* __restrict__ binned,  // [E]
    const int* __restrict__ start,        // [NBIN+1]
    const ushort* __restrict__ kernT,     // [KVOL][4][16][32] bf16
    const float* __restrict__ bias,       // [COUT]
    float* __restrict__ out) {            // [N][COUT]
  __shared__ float tile[RB][COUT + 4];    // stride 68 floats: <=2-way banks
  const int w   = threadIdx.x >> 6;
  const int l   = threadIdx.x & 63;
  const int q   = l & 15;   // A-row / B-col / D-col selector
  const int grp = l >> 4;   // 0..3 (k-chunk / D-row group)
  const int blk = blockIdx.x;

  for (int i = threadIdx.x; i < RB * (COUT + 4); i += NGRP * 64)
    ((float*)tile)[i] = 0.f;

  // B fragments: 3 offsets x 4 cout-tiles, 16B each
  bf16x8 bfrag[KPG][4];
#pragma unroll
  for (int t = 0; t < KPG; ++t)
#pragma unroll
    for (int ct = 0; ct < 4; ++ct)
      bfrag[t][ct] = *(const bf16x8*)(kernT +
          (((size_t)((KPG * w + t) * 4 + ct) * 16 + q) * 32 + grp * 8));
  __syncthreads();

#pragma unroll
  for (int t = 0; t < KPG; ++t) {
    int bin = blk * KVOL + KPG * w + t;
    int s0  = start[bin];
    int cnt = start[bin + 1] - s0;
    for (int base = 0; base < cnt; base += 16) {
      int rem = cnt - base; if (rem > 16) rem = 16;
      uint32_t e = 0;
      if (l < rem) e = binned[s0 + base + l];          // lanes 0..rem-1, coalesced
      uint32_t me = (uint32_t)__shfl((int)e, q);       // entry for my A-row
      bf16x8 a = {0, 0, 0, 0, 0, 0, 0, 0};
      if (q < rem)                                     // padded rows stay zero
        a = *(const bf16x8*)(feat16 + (size_t)(me & 0x3FFFFu) * CIN + grp * 8);
      f32x4 z = {0.f, 0.f, 0.f, 0.f};
      f32x4 acc0 = __builtin_amdgcn_mfma_f32_16x16x32_bf16(a, bfrag[t][0], z, 0, 0, 0);
      f32x4 acc1 = __builtin_amdgcn_mfma_f32_16x16x32_bf16(a, bfrag[t][1], z, 0, 0, 0);
      f32x4 acc2 = __builtin_amdgcn_mfma_f32_16x16x32_bf16(a, bfrag[t][2], z, 0, 0, 0);
      f32x4 acc3 = __builtin_amdgcn_mfma_f32_16x16x32_bf16(a, bfrag[t][3], z, 0, 0, 0);
      // D: col = q (cout within tile), row = grp*4+reg (entry index)
#pragma unroll
      for (int reg = 0; reg < 4; ++reg) {
        int er = grp * 4 + reg;
        uint32_t ee = (uint32_t)__shfl((int)e, er);
        int rl = (int)((ee >> 23) & 63u);
        float* row = tile[rl];
        atomicAdd(&row[0 * 16 + q], acc0[reg]);
        atomicAdd(&row[1 * 16 + q], acc1[reg]);
        atomicAdd(&row[2 * 16 + q], acc2[reg]);
        atomicAdd(&row[3 * 16 + q], acc3[reg]);
      }
    }
  }
  __syncthreads();

  // write tile + bias (rows disjoint across blocks -> plain stores)
  const int R0 = blk * RB;
  for (int i = threadIdx.x; i < RB * 16; i += NGRP * 64) {
    int r = i >> 4, c4 = i & 15;
    float4 v = *(const float4*)&tile[r][c4 * 4];
    float4 b = ((const float4*)bias)[c4];
    v.x += b.x; v.y += b.y; v.z += b.z; v.w += b.w;
    ((float4*)(out + (size_t)(R0 + r) * COUT))[c4] = v;
  }
}

// ---------------------------------------------------------------------------
extern "C" void kernel_launch(void* const* d_in, const int* in_sizes, int n_in,
                              void* d_out, int out_size, void* d_ws, size_t ws_size,
                              hipStream_t stream) {
  const float* feat = (const float*)d_in[0];
  const int2*  kmap = (const int2*)d_in[3];
  const float* kern = (const float*)d_in[4];
  const float* bias = (const float*)d_in[5];
  float* out = (float*)d_out;

  const int N = in_sizes[0] / CIN;          // 200000
  const int M = in_sizes[3] / (2 * KVOL);   // 100000
  const int NBLK = N / RB;                  // 3125
  const int NBIN = NBLK * KVOL;             // 84375

  // workspace
  ushort* feat16 = (ushort*)d_ws;                       // N*CIN bf16
  ushort* kernT  = feat16 + (size_t)N * CIN;            // KVOL*CIN*COUT bf16
  int* count   = (int*)(kernT + (size_t)KVOL * CIN * COUT);
  int* startA  = count + NBIN;                          // NBIN+1
  int* cursor  = startA + NBIN + 1;
  int* partial = cursor + NBIN;                         // 64
  uint32_t* binned = (uint32_t*)(partial + 64);         // KVOL*M

  const int nchunks = (NBIN + SCAN_CHUNK - 1) / SCAN_CHUNK;  // 21

  hipMemsetAsync(count, 0, (size_t)NBIN * sizeof(int), stream);

  hipLaunchKernelGGL(feat_cvt_kernel, dim3((N * CIN / 4 + 255) / 256), dim3(256), 0, stream,
                     feat, feat16, N * CIN / 4);
  hipLaunchKernelGGL(kern_cvt_kernel, dim3(KVOL), dim3(256), 0, stream, kern, kernT);

  dim3 pgrid((M + 255) / 256, KVOL);
  hipLaunchKernelGGL(hist_kernel, pgrid, dim3(256), 0, stream, kmap, count, M);
  hipLaunchKernelGGL(scan_reduce, dim3(nchunks), dim3(256), 0, stream, count, partial, NBIN);
  hipLaunchKernelGGL(scan_partials, dim3(1), dim3(64), 0, stream, partial, nchunks, startA + NBIN);
  hipLaunchKernelGGL(scan_down, dim3(nchunks), dim3(256), 0, stream,
                     count, partial, startA, cursor, NBIN);
  hipLaunchKernelGGL(scatter_kernel, pgrid, dim3(256), 0, stream, kmap, cursor, binned, M);

  hipLaunchKernelGGL(conv_mfma_kernel, dim3(NBLK), dim3(NGRP * 64), 0, stream,
                     feat16, binned, startA, kernT, bias, out);
}

// Round 4
// 809.765 us; speedup vs baseline: 1.8613x; 1.8613x over previous
//
#include <hip/hip_runtime.h>
#include <stdint.h>

#define KVOL 27
#define CIN  32
#define COUT 64
#define RB16 16          // output rows per bin-block (MFMA M)
#define WPG  4           // independent waves per workgroup
#define ENTCAP 640       // max entries per block16 (mean 216, sigma ~15)
#define SCAN_CHUNK 4096

typedef __attribute__((ext_vector_type(8))) short bf16x8;
typedef __attribute__((ext_vector_type(4))) float f32x4;

__device__ __forceinline__ ushort f2bf(float f) {
  uint32_t u = __float_as_uint(f);
  u += 0x7FFFu + ((u >> 16) & 1u);   // RNE
  return (ushort)(u >> 16);
}

// ---------------------------------------------------------------------------
// weights fp32 [KVOL][CIN][COUT] -> bf16 B-frag layout kernT[ko][ct][col16][k32]
// (verified correct in round 3)
// ---------------------------------------------------------------------------
__global__ __launch_bounds__(256) void kern_cvt_kernel(const float* __restrict__ kern,
                                                       ushort* __restrict__ kernT) {
  int tid = blockIdx.x * 256 + threadIdx.x;
  int kc   = tid & 3;
  int colq = (tid >> 2) & 15;
  int ct   = (tid >> 6) & 3;
  int ko   = tid >> 8;
  if (ko >= KVOL) return;
  const float* src = kern + (size_t)ko * CIN * COUT + ct * 16 + colq;
  ushort tmp[8];
#pragma unroll
  for (int j = 0; j < 8; ++j) tmp[j] = f2bf(src[(size_t)(kc * 8 + j) * COUT]);
  ushort* dst = kernT + (((size_t)(ko * 4 + ct) * 16 + colq) * 32 + kc * 8);
#pragma unroll
  for (int j = 0; j < 8; ++j) dst[j] = tmp[j];
}

// ---------------------------------------------------------------------------
// histogram over (block16, k) bins — 2 pairs per thread
// ---------------------------------------------------------------------------
__global__ __launch_bounds__(256) void hist_kernel(const int4* __restrict__ kmap2,
                                                   int* __restrict__ count, int M2) {
  int t = blockIdx.x * 256 + threadIdx.x;
  int k = blockIdx.y;
  if (t < M2) {
    int4 v = kmap2[(size_t)k * M2 + t];
    atomicAdd(&count[(v.y >> 4) * KVOL + k], 1);
    atomicAdd(&count[(v.w >> 4) * KVOL + k], 1);
  }
}

// ---------------------------------------------------------------------------
// scan (3 kernels, generic over nb) — verified round 2/3
// ---------------------------------------------------------------------------
__global__ __launch_bounds__(256) void scan_reduce(const int* __restrict__ count,
                                                   int* __restrict__ partial, int nb) {
  __shared__ int ws[4];
  int t = threadIdx.x;
  int base = blockIdx.x * SCAN_CHUNK + t * 16;
  int s = 0;
#pragma unroll
  for (int i = 0; i < 16; ++i) { int idx = base + i; if (idx < nb) s += count[idx]; }
  for (int d = 32; d; d >>= 1) s += __shfl_down(s, d);
  if ((t & 63) == 0) ws[t >> 6] = s;
  __syncthreads();
  if (t == 0) partial[blockIdx.x] = ws[0] + ws[1] + ws[2] + ws[3];
}

__global__ __launch_bounds__(64) void scan_partials(int* __restrict__ partial,
                                                    int nchunks, int* __restrict__ total_out) {
  int lane = threadIdx.x;
  int run = 0;
  for (int base = 0; base < nchunks; base += 64) {
    int i = base + lane;
    int orig = (i < nchunks) ? partial[i] : 0;
    int v = orig;
    for (int d = 1; d < 64; d <<= 1) { int u = __shfl_up(v, d); if (lane >= d) v += u; }
    if (i < nchunks) partial[i] = run + v - orig;
    run += __shfl(v, 63);
  }
  if (lane == 0) *total_out = run;
}

__global__ __launch_bounds__(256) void scan_down(const int* __restrict__ count,
                                                 const int* __restrict__ partial,
                                                 int* __restrict__ start,
                                                 int* __restrict__ cursor, int nb) {
  __shared__ int wsum[4];
  int t = threadIdx.x, blk = blockIdx.x;
  int base = blk * SCAN_CHUNK + t * 16;
  int v[16]; int s = 0;
#pragma unroll
  for (int i = 0; i < 16; ++i) { int idx = base + i; v[i] = (idx < nb) ? count[idx] : 0; s += v[i]; }
  int lane = t & 63, wv = t >> 6;
  int sv = s;
  for (int d = 1; d < 64; d <<= 1) { int u = __shfl_up(sv, d); if (lane >= d) sv += u; }
  if (lane == 63) wsum[wv] = sv;
  __syncthreads();
  int wbase = 0;
  for (int i = 0; i < wv; ++i) wbase += wsum[i];
  int prefix = partial[blk] + wbase + (sv - s);
#pragma unroll
  for (int i = 0; i < 16; ++i) {
    int idx = base + i;
    if (idx < nb) { start[idx] = prefix; cursor[idx] = prefix; }
    prefix += v[i];
  }
}

// ---------------------------------------------------------------------------
// scatter pairs into bins: entry = in_idx | rowlocal<<18 — 2 pairs per thread
// ---------------------------------------------------------------------------
__global__ __launch_bounds__(256) void scatter_kernel(const int4* __restrict__ kmap2,
                                                      int* __restrict__ cursor,
                                                      uint32_t* __restrict__ binned, int M2) {
  int t = blockIdx.x * 256 + threadIdx.x;
  int k = blockIdx.y;
  if (t < M2) {
    int4 v = kmap2[(size_t)k * M2 + t];
    int b1 = (v.y >> 4) * KVOL + k;
    int p1 = atomicAdd(&cursor[b1], 1);
    binned[p1] = (uint32_t)v.x | ((uint32_t)(v.y & 15) << 18);
    int b2 = (v.w >> 4) * KVOL + k;
    int p2 = atomicAdd(&cursor[b2], 1);
    binned[p2] = (uint32_t)v.z | ((uint32_t)(v.w & 15) << 18);
  }
}

// ---------------------------------------------------------------------------
// main: 1 wave per block16 (4 independent waves/wg, no __syncthreads).
// Per k: pre-sum gathered feat rows into 16x32 f32 LDS staging (pad 36),
// read A-frag, cvt bf16, 4 MFMAs accumulating C across all 27 k.
// Gathers software-pipelined one k ahead (explicit A/B register sets).
// ---------------------------------------------------------------------------
#define STAGE(KK, OFF, CNT, G0, G1, RL, VAL) do {                              \
    int s_  = __shfl(sv, (KK));                                                \
    int s1_ = __shfl(sv, (KK) + 1);                                            \
    OFF = s_ - base0; CNT = s1_ - s_;                                          \
    int c0_ = CNT < 16 ? CNT : 16;                                             \
    VAL = (eidx < c0_);                                                        \
    uint32_t e_ = ents[wv][OFF + (VAL ? eidx : 0)];                            \
    RL = (int)(e_ >> 18);                                                      \
    const float* fp_ = feat + (size_t)(e_ & 0x3FFFFu) * CIN + part * 8;        \
    if (VAL) { G0 = *(const float4*)fp_; G1 = *(const float4*)(fp_ + 4); }     \
    else     { G0 = zf; G1 = zf; }                                             \
  } while (0)

#define CONSUME(KK, BUF, OFF, CNT, G0, G1, RL, VAL) do {                       \
    const ushort* kb_ = kernT + ((size_t)(KK) * 64 + q) * 32 + grp * 8;        \
    bf16x8 bf0_ = *(const bf16x8*)(kb_);                                       \
    bf16x8 bf1_ = *(const bf16x8*)(kb_ + 512);                                 \
    bf16x8 bf2_ = *(const bf16x8*)(kb_ + 1024);                                \
    bf16x8 bf3_ = *(const bf16x8*)(kb_ + 1536);                                \
    float* sp_ = &stage[wv][BUF][0][0];                                        \
    if (VAL) {                                                                 \
      float* rp_ = sp_ + RL * 36 + part * 8;                                   \
      atomicAdd(rp_ + 0, G0.x); atomicAdd(rp_ + 1, G0.y);                      \
      atomicAdd(rp_ + 2, G0.z); atomicAdd(rp_ + 3, G0.w);                      \
      atomicAdd(rp_ + 4, G1.x); atomicAdd(rp_ + 5, G1.y);                      \
      atomicAdd(rp_ + 6, G1.z); atomicAdd(rp_ + 7, G1.w);                      \
    }                                                                          \
    for (int off_ = 16; off_ < CNT; off_ += 16) {  /* rare: cnt>16 */          \
      bool v_ = (off_ + eidx < CNT);                                           \
      uint32_t e_ = ents[wv][OFF + off_ + (v_ ? eidx : 0)];                    \
      if (v_) {                                                                \
        const float* fp_ = feat + (size_t)(e_ & 0x3FFFFu) * CIN + part * 8;    \
        float4 h0_ = *(const float4*)fp_;                                      \
        float4 h1_ = *(const float4*)(fp_ + 4);                                \
        float* rp_ = sp_ + (int)(e_ >> 18) * 36 + part * 8;                    \
        atomicAdd(rp_ + 0, h0_.x); atomicAdd(rp_ + 1, h0_.y);                  \
        atomicAdd(rp_ + 2, h0_.z); atomicAdd(rp_ + 3, h0_.w);                  \
        atomicAdd(rp_ + 4, h1_.x); atomicAdd(rp_ + 5, h1_.y);                  \
        atomicAdd(rp_ + 6, h1_.z); atomicAdd(rp_ + 7, h1_.w);                  \
      }                                                                        \
    }                                                                          \
    asm volatile("s_waitcnt lgkmcnt(0)" ::: "memory");                         \
    const float* ar_ = sp_ + q * 36 + grp * 8;                                 \
    float4 u0_ = *(const float4*)ar_;                                          \
    float4 u1_ = *(const float4*)(ar_ + 4);                                    \
    bf16x8 af_;                                                                \
    af_[0] = (short)f2bf(u0_.x); af_[1] = (short)f2bf(u0_.y);                  \
    af_[2] = (short)f2bf(u0_.z); af_[3] = (short)f2bf(u0_.w);                  \
    af_[4] = (short)f2bf(u1_.x); af_[5] = (short)f2bf(u1_.y);                  \
    af_[6] = (short)f2bf(u1_.z); af_[7] = (short)f2bf(u1_.w);                  \
    acc0 = __builtin_amdgcn_mfma_f32_16x16x32_bf16(af_, bf0_, acc0, 0, 0, 0);  \
    acc1 = __builtin_amdgcn_mfma_f32_16x16x32_bf16(af_, bf1_, acc1, 0, 0, 0);  \
    acc2 = __builtin_amdgcn_mfma_f32_16x16x32_bf16(af_, bf2_, acc2, 0, 0, 0);  \
    acc3 = __builtin_amdgcn_mfma_f32_16x16x32_bf16(af_, bf3_, acc3, 0, 0, 0);  \
    asm volatile("s_waitcnt lgkmcnt(0)" ::: "memory");                         \
    float2* zp_ = (float2*)sp_;                                                \
    zp_[l] = z2; zp_[l + 64] = z2; zp_[l + 128] = z2;                          \
    if (l < 32) zp_[l + 256] = z2;                                             \
    zp_[l + 192] = z2;                                                         \
  } while (0)

__global__ __launch_bounds__(256, 4) void conv_mfma2(
    const float* __restrict__ feat,       // [N][CIN] f32
    const uint32_t* __restrict__ binned,  // [E]
    const int* __restrict__ start,        // [NBIN+1]
    const ushort* __restrict__ kernT,     // [KVOL][4][16][32] bf16
    const float* __restrict__ bias,       // [COUT]
    float* __restrict__ out) {            // [N][COUT]
  __shared__ float stage[WPG][2][RB16][36];   // padded: ~2-way banks
  __shared__ uint32_t ents[WPG][ENTCAP];
  const int wv  = threadIdx.x >> 6;
  const int l   = threadIdx.x & 63;
  const int q   = l & 15;          // A-row / B-col / D-col
  const int grp = l >> 4;          // k-chunk / D-row group
  const int eidx = l >> 2;         // entry slot 0..15 (gather)
  const int part = l & 3;          // 8-float chunk   (gather)
  const int blk = blockIdx.x * WPG + wv;
  const float4 zf = {0.f, 0.f, 0.f, 0.f};
  const float2 z2 = {0.f, 0.f};

  // prefetch all 28 segment bounds into lane registers (no per-k global trip)
  int sv = 0;
  if (l <= KVOL) sv = start[blk * KVOL + l];
  const int base0 = __shfl(sv, 0);
  int total = __shfl(sv, KVOL) - base0;
  if (total > ENTCAP) total = ENTCAP;   // impossible statistically; avoids corruption

  // copy block16's entries to LDS (wave-local; coalesced)
  for (int i = l; i < total; i += 64) ents[wv][i] = binned[base0 + i];

  // zero both staging buffers (1152 floats)
  {
    float2* zp = (float2*)&stage[wv][0][0][0];
#pragma unroll
    for (int i = 0; i < 9; ++i) zp[l + i * 64] = z2;
  }

  float bv0 = bias[q], bv1 = bias[16 + q], bv2 = bias[32 + q], bv3 = bias[48 + q];

  asm volatile("s_waitcnt lgkmcnt(0)" ::: "memory");   // copy+zero visible

  f32x4 acc0 = {0,0,0,0}, acc1 = {0,0,0,0}, acc2 = {0,0,0,0}, acc3 = {0,0,0,0};
  int offA, cntA, rlA; bool valA; float4 gA0, gA1;
  int offB, cntB, rlB; bool valB; float4 gB0, gB1;

  STAGE(0, offA, cntA, gA0, gA1, rlA, valA);
  for (int k = 0; k < KVOL - 1; k += 2) {
    STAGE(k + 1, offB, cntB, gB0, gB1, rlB, valB);
    CONSUME(k, 0, offA, cntA, gA0, gA1, rlA, valA);
    STAGE(k + 2, offA, cntA, gA0, gA1, rlA, valA);
    CONSUME(k + 1, 1, offB, cntB, gB0, gB1, rlB, valB);
  }
  CONSUME(KVOL - 1, 0, offA, cntA, gA0, gA1, rlA, valA);

  // epilogue: D col=q, row=grp*4+reg; rows disjoint across waves -> plain stores
  const int R0 = blk * RB16;
#pragma unroll
  for (int reg = 0; reg < 4; ++reg) {
    float* op = out + (size_t)(R0 + grp * 4 + reg) * COUT + q;
    op[0]  = acc0[reg] + bv0;
    op[16] = acc1[reg] + bv1;
    op[32] = acc2[reg] + bv2;
    op[48] = acc3[reg] + bv3;
  }
}

// ---------------------------------------------------------------------------
extern "C" void kernel_launch(void* const* d_in, const int* in_sizes, int n_in,
                              void* d_out, int out_size, void* d_ws, size_t ws_size,
                              hipStream_t stream) {
  const float* feat = (const float*)d_in[0];
  const int4*  kmap2 = (const int4*)d_in[3];   // 2 pairs per int4
  const float* kern = (const float*)d_in[4];
  const float* bias = (const float*)d_in[5];
  float* out = (float*)d_out;

  const int N = in_sizes[0] / CIN;            // 200000
  const int M = in_sizes[3] / (2 * KVOL);     // 100000
  const int M2 = M / 2;                       // 50000
  const int NBLK16 = N / RB16;                // 12500
  const int NBIN = NBLK16 * KVOL;             // 337500

  // workspace
  ushort* kernT = (ushort*)d_ws;                        // 55296 ushorts
  int* count    = (int*)(kernT + (size_t)KVOL * CIN * COUT);
  int* startA   = count + NBIN;                         // NBIN+1
  int* cursor   = startA + NBIN + 1;
  int* partial  = cursor + NBIN;                        // 128
  uint32_t* binned = (uint32_t*)(partial + 128);        // KVOL*M

  const int nchunks = (NBIN + SCAN_CHUNK - 1) / SCAN_CHUNK;   // 83

  hipMemsetAsync(count, 0, (size_t)NBIN * sizeof(int), stream);
  hipLaunchKernelGGL(kern_cvt_kernel, dim3(KVOL), dim3(256), 0, stream, kern, kernT);

  dim3 pgrid((M2 + 255) / 256, KVOL);
  hipLaunchKernelGGL(hist_kernel, pgrid, dim3(256), 0, stream, kmap2, count, M2);
  hipLaunchKernelGGL(scan_reduce, dim3(nchunks), dim3(256), 0, stream, count, partial, NBIN);
  hipLaunchKernelGGL(scan_partials, dim3(1), dim3(64), 0, stream, partial, nchunks, startA + NBIN);
  hipLaunchKernelGGL(scan_down, dim3(nchunks), dim3(256), 0, stream,
                     count, partial, startA, cursor, NBIN);
  hipLaunchKernelGGL(scatter_kernel, pgrid, dim3(256), 0, stream, kmap2, cursor, binned, M2);

  hipLaunchKernelGGL(conv_mfma2, dim3(NBLK16 / WPG), dim3(256), 0, stream,
                     feat, binned, startA, kernT, bias, out);
}